// Round 1
// baseline (304.429 us; speedup 1.0000x reference)
//
#include <hip/hip_runtime.h>
#include <stdint.h>

#define N_SAMP 131072
#define DIN    256
#define HIDN   1024
#define BROWS  128           // rows per block
#define HCH    64            // hidden units per chunk
#define NCHUNK (HIDN / HCH)  // 16
#define LDSP   264           // LDS row pitch in bf16 elems (256 + 8 pad, keeps 16B align)

typedef __attribute__((ext_vector_type(8))) short short8;
typedef __attribute__((ext_vector_type(4))) float f32x4;

__device__ __forceinline__ unsigned short f2bf(float f) {
  unsigned u = __float_as_uint(f);
  u += 0x7fffu + ((u >> 16) & 1u);   // round-to-nearest-even (inputs are finite)
  return (unsigned short)(u >> 16);
}

__device__ __forceinline__ short8 pack8(float4 a, float4 b) {
  short8 r;
  r[0] = (short)f2bf(a.x); r[1] = (short)f2bf(a.y);
  r[2] = (short)f2bf(a.z); r[3] = (short)f2bf(a.w);
  r[4] = (short)f2bf(b.x); r[5] = (short)f2bf(b.y);
  r[6] = (short)f2bf(b.z); r[7] = (short)f2bf(b.w);
  return r;
}

// Pre-convert W1 (fp32 [1024][256]) -> bf16 row-major in workspace.
__global__ __launch_bounds__(256) void w1_to_bf16(const float* __restrict__ W1,
                                                  unsigned short* __restrict__ o) {
  int i = blockIdx.x * 256 + threadIdx.x;          // 65536 threads, 4 elems each
  float4 f = ((const float4*)W1)[i];
  ushort4 v;
  v.x = f2bf(f.x); v.y = f2bf(f.y); v.z = f2bf(f.z); v.w = f2bf(f.w);
  ((ushort4*)o)[i] = v;
}

// Fused: h = relu(x@W1^T + b1); y = dot(We[c[num]], h) + be[...]; out = sigmoid(y)
template <bool WBF>
__global__ __launch_bounds__(256, 3) void fused_kernel(
    const float* __restrict__ x,
    const float* __restrict__ W1f,
    const unsigned short* __restrict__ W1b,
    const float* __restrict__ b1,
    const float* __restrict__ We,   // [100][1024]
    const float* __restrict__ be,   // [100]
    const int* __restrict__ num,    // [N]
    const int* __restrict__ c,      // [100]
    float* __restrict__ out)        // [N]
{
  __shared__ unsigned short Wt[HCH * LDSP];  // 33792 B
  __shared__ int e_sh[BROWS];

  const int tid  = threadIdx.x;
  const int lane = tid & 63;
  const int w    = tid >> 6;        // wave 0..3
  const int m    = lane & 15;       // MFMA row/col-within-tile lane coord
  const int quad = lane >> 4;       // 0..3
  const int R0   = blockIdx.x * BROWS;

  if (tid < BROWS) {
    int nv = num[R0 + tid];
    e_sh[tid] = c[nv];
  }

  // ---- A fragments: 2 row-tiles x 8 k-steps, kept in registers for whole kernel.
  // A[m=lane&15][k=quad*8+j] per tile; k0 = s*32 + quad*8.
  short8 afr[2][8];
  {
    const float* xr0 = x + (size_t)(R0 + w * 32 + m) * DIN + quad * 8;
#pragma unroll
    for (int t = 0; t < 2; ++t) {
      const float* xr = xr0 + (size_t)t * 16 * DIN;
#pragma unroll
      for (int s = 0; s < 8; ++s) {
        float4 f0 = *(const float4*)(xr + s * 32);
        float4 f1 = *(const float4*)(xr + s * 32 + 4);
        afr[t][s] = pack8(f0, f1);
      }
    }
  }

  __syncthreads();  // e_sh ready

  int eid[2][4];
#pragma unroll
  for (int t = 0; t < 2; ++t)
#pragma unroll
    for (int r = 0; r < 4; ++r)
      eid[t][r] = e_sh[w * 32 + t * 16 + quad * 4 + r];

  float yacc[2][4] = {{0.f, 0.f, 0.f, 0.f}, {0.f, 0.f, 0.f, 0.f}};

  for (int ch = 0; ch < NCHUNK; ++ch) {
    const int hb = ch * HCH;

    // ---- stage W1 chunk [64][256] into LDS as bf16 (2048 16B-groups, 8/thread)
    if (WBF) {
      const uint4* Wg = (const uint4*)(W1b + (size_t)hb * DIN);
#pragma unroll
      for (int j = 0; j < 8; ++j) {
        int id = tid + j * 256;
        int r = id >> 5, kg = id & 31;
        uint4 v = Wg[id];
        *(uint4*)&Wt[r * LDSP + kg * 8] = v;
      }
    } else {
      const float4* Wg = (const float4*)(W1f + (size_t)hb * DIN);
#pragma unroll
      for (int j = 0; j < 8; ++j) {
        int id = tid + j * 256;
        int r = id >> 5, kg = id & 31;
        float4 f0 = Wg[id * 2];
        float4 f1 = Wg[id * 2 + 1];
        short8 v = pack8(f0, f1);
        *(short8*)&Wt[r * LDSP + kg * 8] = v;
      }
    }
    __syncthreads();

    // ---- MFMA: C[t][nt] = x-tile @ W1-chunk^T  (16x16 tiles, K=256)
    f32x4 acc[2][4];
#pragma unroll
    for (int t = 0; t < 2; ++t)
#pragma unroll
      for (int nt = 0; nt < 4; ++nt)
        acc[t][nt] = (f32x4){0.f, 0.f, 0.f, 0.f};

#pragma unroll
    for (int s = 0; s < 8; ++s) {
      short8 bfr[4];
#pragma unroll
      for (int nt = 0; nt < 4; ++nt)
        bfr[nt] = *(const short8*)&Wt[(nt * 16 + m) * LDSP + s * 32 + quad * 8];
#pragma unroll
      for (int t = 0; t < 2; ++t)
#pragma unroll
        for (int nt = 0; nt < 4; ++nt)
          acc[t][nt] = __builtin_amdgcn_mfma_f32_16x16x32_bf16(
              afr[t][s], bfr[nt], acc[t][nt], 0, 0, 0);
    }
    __syncthreads();  // protect Wt before next stage; epilogue below overlaps

    // ---- epilogue: +b1, relu, * gathered We row, accumulate per-row y
    // C layout: col = lane&15 (within tile), row = quad*4 + reg  [m89/m91]
#pragma unroll
    for (int nt = 0; nt < 4; ++nt) {
      int col = hb + nt * 16 + m;
      float bv = b1[col];
      const float* Wec = We + col;
#pragma unroll
      for (int t = 0; t < 2; ++t)
#pragma unroll
        for (int r = 0; r < 4; ++r) {
          float h = acc[t][nt][r] + bv;
          h = fmaxf(h, 0.f);
          yacc[t][r] = fmaf(h, Wec[(size_t)eid[t][r] * HIDN], yacc[t][r]);
        }
    }
  }

  // ---- reduce partial y across the 16 lanes of each quad-group
#pragma unroll
  for (int t = 0; t < 2; ++t)
#pragma unroll
    for (int r = 0; r < 4; ++r) {
      float v = yacc[t][r];
      v += __shfl_xor(v, 1);
      v += __shfl_xor(v, 2);
      v += __shfl_xor(v, 4);
      v += __shfl_xor(v, 8);
      yacc[t][r] = v;
    }

  if (m == 0) {
#pragma unroll
    for (int t = 0; t < 2; ++t)
#pragma unroll
      for (int r = 0; r < 4; ++r) {
        int row = R0 + w * 32 + t * 16 + quad * 4 + r;
        float yy = yacc[t][r] + be[eid[t][r]];
        out[row] = 1.f / (1.f + __expf(-yy));
      }
  }
}

extern "C" void kernel_launch(void* const* d_in, const int* in_sizes, int n_in,
                              void* d_out, int out_size, void* d_ws, size_t ws_size,
                              hipStream_t stream) {
  const float* x   = (const float*)d_in[0];
  const float* W1  = (const float*)d_in[1];
  const float* b1  = (const float*)d_in[2];
  const float* We  = (const float*)d_in[3];
  const float* be  = (const float*)d_in[4];
  const int*   num = (const int*)d_in[5];
  const int*   c   = (const int*)d_in[6];
  float* out = (float*)d_out;

  const size_t w1bf_bytes = (size_t)HIDN * DIN * sizeof(unsigned short);
  const bool usebf = ws_size >= w1bf_bytes;
  unsigned short* w1bf = (unsigned short*)d_ws;

  if (usebf) {
    w1_to_bf16<<<dim3((HIDN * DIN / 4) / 256), dim3(256), 0, stream>>>(W1, w1bf);
    fused_kernel<true><<<dim3(N_SAMP / BROWS), dim3(256), 0, stream>>>(
        x, W1, w1bf, b1, We, be, num, c, out);
  } else {
    fused_kernel<false><<<dim3(N_SAMP / BROWS), dim3(256), 0, stream>>>(
        x, W1, w1bf, b1, We, be, num, c, out);
  }
}